// Round 17
// baseline (88.237 us; speedup 1.0000x reference)
//
#include <hip/hip_runtime.h>
#include <hip/hip_bf16.h>
#include <hip/hip_fp16.h>

// ---------------------------------------------------------------------------
// 2-layer GCN (PyG GCNConv semantics) on MI355X.
//   out[d] = relu( dinv[d]*( sum_e H'[src_e] + H'[d] ) + b ),  H' = dinv .* (X@W)
// R1..R11: CSR-gather; binned scatter; register-tiled GEMM; fp16 H'; fused
//          layer1-gather+layer2-GEMM. 103.5us.
// R12: partial-hist scan -- REGRESSED. R13: revert +128-row bins. 104.2us.
// R14: cooperative 5-in-1 preprocess -- REGRESSED (grid.sync spin). 185us.
// R15: fixed-capacity bins (no hist/scan pre-pass). 88.5us.
// R16: ushort edge_src; 512-thread preprocess blocks. 86.7us.
// R16->R17: k_agg_gemm 64 nodes/block @512 threads (half the W2-staging
//   instances + 64x64x64 GEMM per barrier instead of 32x64x64).
// ---------------------------------------------------------------------------

#define THREADS 256
#define BINSH 7                   // 128 rows per bin
#define BINW (1 << BINSH)
#define MAXBINS 512               // >= nbins = ceil(50000/128) = 391
#define CAPSH 12                  // 4096 slots per bin (mean fill ~2048)
#define CAP (1 << CAPSH)

__device__ inline int wave_incl_scan(int v, int lane) {
#pragma unroll
    for (int ofs = 1; ofs < 64; ofs <<= 1) {
        int t = __shfl_up(v, ofs, 64);
        if (lane >= ofs) v += t;
    }
    return v;
}

// --- init per-bin cursors to bin*CAP ---------------------------------------
__global__ void k_init_cursor(int* __restrict__ bin_cursor, int nbins) {
    int i = blockIdx.x * blockDim.x + threadIdx.x;
    if (i < nbins) bin_cursor[i] = i << CAPSH;
}

// --- pass 1: bin edges by 128-row dst-bin into fixed-cap slots -------------
// 512 threads x 8 edges = 4096 edges/block. packed = (src<<7) | (dst & 127).
__global__ __launch_bounds__(512)
void k_bin_scatter(const int* __restrict__ src, const int* __restrict__ dst,
                   int* __restrict__ bin_cursor, unsigned int* __restrict__ edge_binned,
                   int n_edges) {
    __shared__ int cnt[512];
    __shared__ int lbase[512];
    __shared__ int gbase[512];
    __shared__ int run[512];
    __shared__ int wsum[8];
    __shared__ unsigned int staged[4096];
    __shared__ unsigned short binarr[4096];
    const int tid = threadIdx.x;
    const int lane = tid & 63;
    const int wid = tid >> 6;
    const int base = blockIdx.x * 4096 + tid * 8;
    cnt[tid] = 0;
    run[tid] = 0;
    __syncthreads();

    int dv[8], sv[8];
    int nv = (base < n_edges) ? min(8, n_edges - base) : 0;
    if (nv == 8) {
        int4 a = *(const int4*)&dst[base];
        int4 b = *(const int4*)&dst[base + 4];
        dv[0] = a.x; dv[1] = a.y; dv[2] = a.z; dv[3] = a.w;
        dv[4] = b.x; dv[5] = b.y; dv[6] = b.z; dv[7] = b.w;
        a = *(const int4*)&src[base];
        b = *(const int4*)&src[base + 4];
        sv[0] = a.x; sv[1] = a.y; sv[2] = a.z; sv[3] = a.w;
        sv[4] = b.x; sv[5] = b.y; sv[6] = b.z; sv[7] = b.w;
    } else {
        for (int j = 0; j < nv; ++j) {
            dv[j] = dst[base + j];
            sv[j] = src[base + j];
        }
    }
    for (int j = 0; j < nv; ++j) atomicAdd(&cnt[dv[j] >> BINSH], 1);
    __syncthreads();
    int mycnt = cnt[tid];
    int s = wave_incl_scan(mycnt, lane);
    if (lane == 63) wsum[wid] = s;
    __syncthreads();
    if (wid == 0) {
        int t = (lane < 8) ? wsum[lane] : 0;
        int t2 = wave_incl_scan(t, lane);
        if (lane < 8) wsum[lane] = t2;
    }
    __syncthreads();
    int incl = s + ((wid > 0) ? wsum[wid - 1] : 0);
    lbase[tid] = incl - mycnt;
    if (mycnt > 0) gbase[tid] = atomicAdd(&bin_cursor[tid], mycnt);
    __syncthreads();
    for (int j = 0; j < nv; ++j) {
        int bn = dv[j] >> BINSH;
        int rank = atomicAdd(&run[bn], 1);
        int lp = lbase[bn] + rank;
        staged[lp] = ((unsigned)sv[j] << BINSH) | (unsigned)(dv[j] & (BINW - 1));
        binarr[lp] = (unsigned short)bn;
    }
    __syncthreads();
    int tot = wsum[7];
    for (int slot = tid; slot < tot; slot += 512) {
        int bn = binarr[slot];
        edge_binned[gbase[bn] + (slot - lbase[bn])] = staged[slot];
    }
}

// --- pass 2: per-bin degree count + scan + exact CSR (ushort) + metadata ---
// one block (512 thr) per 128-row bin; bin window = [b*CAP, bin_cursor[b]).
__global__ __launch_bounds__(512)
void k_csr_build(const unsigned int* __restrict__ edge_binned,
                 const int* __restrict__ bin_cursor,
                 unsigned short* __restrict__ edge_src,
                 int* __restrict__ offsets, int* __restrict__ degi,
                 float* __restrict__ dinv, int n_nodes) {
    __shared__ int lcnt[BINW];
    __shared__ int sc[BINW];
    __shared__ int lcur[BINW];
    const int b = blockIdx.x;
    const int node0 = b << BINSH;
    const int tid = threadIdx.x;
    const int ebeg = b << CAPSH;
    const int eend = bin_cursor[b];

    if (tid < BINW) lcnt[tid] = 0;
    __syncthreads();
    for (int k = ebeg + tid; k < eend; k += 512)
        atomicAdd(&lcnt[edge_binned[k] & (BINW - 1u)], 1);
    __syncthreads();

    if (tid < BINW) sc[tid] = lcnt[tid];
    __syncthreads();
    for (int ofs = 1; ofs < BINW; ofs <<= 1) {
        int v = 0;
        if (tid < BINW && tid >= ofs) v = sc[tid - ofs];
        __syncthreads();
        if (tid < BINW) sc[tid] += v;
        __syncthreads();
    }
    if (tid < BINW) {
        int cntv = lcnt[tid];
        int excl = ebeg + sc[tid] - cntv;
        lcur[tid] = excl;
        int node = node0 + tid;
        if (node < n_nodes) {
            offsets[node] = excl;
            degi[node] = cntv;
            dinv[node] = 1.0f / sqrtf((float)(1 + cntv));
        }
    }
    __syncthreads();
    for (int k = ebeg + tid; k < eend; k += 512) {
        unsigned p = edge_binned[k];
        int pos = atomicAdd(&lcur[p & (BINW - 1u)], 1);
        edge_src[pos] = (unsigned short)(p >> BINSH);
    }
}

// --- register-tiled GEMM: H'[r,:] = fp16( dinv[r] * (X[r,:K] @ W[K,64]) ) --
template <int K>
__global__ __launch_bounds__(256, 2)
void k_gemm(const float* __restrict__ X, const float* __restrict__ W,
            const float* __restrict__ dinv, __half* __restrict__ H, int n_rows) {
    constexpr int KQ = K / 4;
    constexpr int RSH = (KQ == 32) ? 5 : 4;
    __shared__ float sW[K * 64];
    __shared__ float sX[64 * K];
    const int tid = threadIdx.x;
    const int row0 = blockIdx.x * 64;

#pragma unroll
    for (int it = 0; it < (K * 64 / 4) / THREADS; ++it) {
        int idx = it * THREADS + tid;
        ((float4*)sW)[idx] = ((const float4*)W)[idx];
    }
#pragma unroll
    for (int it = 0; it < (64 * KQ) / THREADS; ++it) {
        int idx = it * THREADS + tid;
        int kq = idx & (KQ - 1);
        int r = idx >> RSH;
        float4 g = make_float4(0.f, 0.f, 0.f, 0.f);
        int grow = row0 + r;
        if (grow < n_rows) g = *(const float4*)&X[(size_t)grow * K + 4 * kq];
        *(float4*)&sX[r * K + ((kq ^ (r & 7)) << 2)] = g;
    }
    __syncthreads();

    const int tx = tid & 15;
    const int ty = tid >> 4;
    float acc[4][4];
#pragma unroll
    for (int i = 0; i < 4; ++i)
#pragma unroll
        for (int j = 0; j < 4; ++j) acc[i][j] = 0.f;

#pragma unroll 2
    for (int k4 = 0; k4 < KQ; ++k4) {
        float4 b0 = *(const float4*)&sW[(4 * k4 + 0) * 64 + 4 * tx];
        float4 b1 = *(const float4*)&sW[(4 * k4 + 1) * 64 + 4 * tx];
        float4 b2 = *(const float4*)&sW[(4 * k4 + 2) * 64 + 4 * tx];
        float4 b3 = *(const float4*)&sW[(4 * k4 + 3) * 64 + 4 * tx];
#pragma unroll
        for (int i = 0; i < 4; ++i) {
            int r = 4 * ty + i;
            float4 a = *(const float4*)&sX[r * K + ((k4 ^ (r & 7)) << 2)];
            acc[i][0] = fmaf(a.x, b0.x, acc[i][0]);
            acc[i][1] = fmaf(a.x, b0.y, acc[i][1]);
            acc[i][2] = fmaf(a.x, b0.z, acc[i][2]);
            acc[i][3] = fmaf(a.x, b0.w, acc[i][3]);
            acc[i][0] = fmaf(a.y, b1.x, acc[i][0]);
            acc[i][1] = fmaf(a.y, b1.y, acc[i][1]);
            acc[i][2] = fmaf(a.y, b1.z, acc[i][2]);
            acc[i][3] = fmaf(a.y, b1.w, acc[i][3]);
            acc[i][0] = fmaf(a.z, b2.x, acc[i][0]);
            acc[i][1] = fmaf(a.z, b2.y, acc[i][1]);
            acc[i][2] = fmaf(a.z, b2.z, acc[i][2]);
            acc[i][3] = fmaf(a.z, b2.w, acc[i][3]);
            acc[i][0] = fmaf(a.w, b3.x, acc[i][0]);
            acc[i][1] = fmaf(a.w, b3.y, acc[i][1]);
            acc[i][2] = fmaf(a.w, b3.z, acc[i][2]);
            acc[i][3] = fmaf(a.w, b3.w, acc[i][3]);
        }
    }

#pragma unroll
    for (int i = 0; i < 4; ++i) {
        int grow = row0 + 4 * ty + i;
        if (grow < n_rows) {
            float dvv = dinv[grow];
            union { __half2 h[2]; uint2 u; } pk;
            pk.h[0] = __floats2half2_rn(acc[i][0] * dvv, acc[i][1] * dvv);
            pk.h[1] = __floats2half2_rn(acc[i][2] * dvv, acc[i][3] * dvv);
            *(uint2*)&H[(size_t)grow * 64 + 4 * tx] = pk.u;
        }
    }
}

// --- fp16 row accumulate helper --------------------------------------------
__device__ inline void acc_row16(float2 acc[4], uint4 u) {
    const __half2* hp = (const __half2*)&u;
    float2 a = __half22float2(hp[0]);
    float2 b = __half22float2(hp[1]);
    float2 c = __half22float2(hp[2]);
    float2 d = __half22float2(hp[3]);
    acc[0].x += a.x; acc[0].y += a.y;
    acc[1].x += b.x; acc[1].y += b.y;
    acc[2].x += c.x; acc[2].y += c.y;
    acc[3].x += d.x; acc[3].y += d.y;
}

// gather one node's aggregate: acc = H'[node] + sum_e H'[src_e], half8 slot l
__device__ inline void gather_node(float2 acc[4], const __half* __restrict__ Hp,
                                   int node, int l, const int* __restrict__ offsets,
                                   const int* __restrict__ degi,
                                   const unsigned short* __restrict__ edge_src) {
    acc[0] = make_float2(0.f, 0.f); acc[1] = make_float2(0.f, 0.f);
    acc[2] = make_float2(0.f, 0.f); acc[3] = make_float2(0.f, 0.f);
    acc_row16(acc, *(const uint4*)(Hp + ((size_t)node << 6) + (l << 3)));  // self
    int start = offsets[node];
    int cnt = degi[node];
    int k = 0;
    for (; k + 8 <= cnt; k += 8) {
        int s0 = edge_src[start + k];
        int s1 = edge_src[start + k + 1];
        int s2 = edge_src[start + k + 2];
        int s3 = edge_src[start + k + 3];
        int s4 = edge_src[start + k + 4];
        int s5 = edge_src[start + k + 5];
        int s6 = edge_src[start + k + 6];
        int s7 = edge_src[start + k + 7];
        uint4 u0 = *(const uint4*)(Hp + ((size_t)s0 << 6) + (l << 3));
        uint4 u1 = *(const uint4*)(Hp + ((size_t)s1 << 6) + (l << 3));
        uint4 u2 = *(const uint4*)(Hp + ((size_t)s2 << 6) + (l << 3));
        uint4 u3 = *(const uint4*)(Hp + ((size_t)s3 << 6) + (l << 3));
        uint4 u4 = *(const uint4*)(Hp + ((size_t)s4 << 6) + (l << 3));
        uint4 u5 = *(const uint4*)(Hp + ((size_t)s5 << 6) + (l << 3));
        uint4 u6 = *(const uint4*)(Hp + ((size_t)s6 << 6) + (l << 3));
        uint4 u7 = *(const uint4*)(Hp + ((size_t)s7 << 6) + (l << 3));
        acc_row16(acc, u0); acc_row16(acc, u1); acc_row16(acc, u2); acc_row16(acc, u3);
        acc_row16(acc, u4); acc_row16(acc, u5); acc_row16(acc, u6); acc_row16(acc, u7);
    }
    for (; k + 4 <= cnt; k += 4) {
        int s0 = edge_src[start + k];
        int s1 = edge_src[start + k + 1];
        int s2 = edge_src[start + k + 2];
        int s3 = edge_src[start + k + 3];
        uint4 u0 = *(const uint4*)(Hp + ((size_t)s0 << 6) + (l << 3));
        uint4 u1 = *(const uint4*)(Hp + ((size_t)s1 << 6) + (l << 3));
        uint4 u2 = *(const uint4*)(Hp + ((size_t)s2 << 6) + (l << 3));
        uint4 u3 = *(const uint4*)(Hp + ((size_t)s3 << 6) + (l << 3));
        acc_row16(acc, u0); acc_row16(acc, u1); acc_row16(acc, u2); acc_row16(acc, u3);
    }
    for (; k < cnt; ++k) {
        int s0 = edge_src[start + k];
        acc_row16(acc, *(const uint4*)(Hp + ((size_t)s0 << 6) + (l << 3)));
    }
}

// --- fused: layer-1 gather+epilogue -> LDS tile -> layer-2 GEMM -> h2 fp16 -
// 512 threads = 64 nodes/block (8 lanes x half8 each); 64x64x64 GEMM phase.
__global__ __launch_bounds__(512)
void k_agg_gemm(const __half* __restrict__ Hp, const int* __restrict__ offsets,
                const int* __restrict__ degi, const unsigned short* __restrict__ edge_src,
                const float* __restrict__ dinv, const float* __restrict__ b1,
                const float* __restrict__ W2, __half* __restrict__ H2, int n_nodes) {
    __shared__ float sX[64 * 64];
    __shared__ float sW[64 * 64];
    const int tid = threadIdx.x;
    const int node0 = blockIdx.x * 64;

#pragma unroll
    for (int it = 0; it < 2; ++it)
        ((float4*)sW)[it * 512 + tid] = ((const float4*)W2)[it * 512 + tid];

    {
        const int r = tid >> 3;          // node_local 0..63
        const int l = tid & 7;           // half8 slot
        const int node = node0 + r;
        float v[8];
        if (node < n_nodes) {
            float2 acc[4];
            gather_node(acc, Hp, node, l, offsets, degi, edge_src);
            float dv = dinv[node];
            const float* bp = b1 + (l << 3);
            v[0] = fmaxf(fmaf(acc[0].x, dv, bp[0]), 0.f);
            v[1] = fmaxf(fmaf(acc[0].y, dv, bp[1]), 0.f);
            v[2] = fmaxf(fmaf(acc[1].x, dv, bp[2]), 0.f);
            v[3] = fmaxf(fmaf(acc[1].y, dv, bp[3]), 0.f);
            v[4] = fmaxf(fmaf(acc[2].x, dv, bp[4]), 0.f);
            v[5] = fmaxf(fmaf(acc[2].y, dv, bp[5]), 0.f);
            v[6] = fmaxf(fmaf(acc[3].x, dv, bp[6]), 0.f);
            v[7] = fmaxf(fmaf(acc[3].y, dv, bp[7]), 0.f);
        } else {
#pragma unroll
            for (int j = 0; j < 8; ++j) v[j] = 0.f;
        }
        *(float4*)&sX[r * 64 + (((2 * l + 0) ^ (r & 7)) << 2)] =
            make_float4(v[0], v[1], v[2], v[3]);
        *(float4*)&sX[r * 64 + (((2 * l + 1) ^ (r & 7)) << 2)] =
            make_float4(v[4], v[5], v[6], v[7]);
    }
    __syncthreads();

    // GEMM phase: 64 rows x 64 cols, 512 threads -> 2x4 outputs per thread
    const int tx = tid & 15;             // col group: cols 4*tx..4*tx+3
    const int ty = tid >> 4;             // 0..31 -> rows 2*ty, 2*ty+1
    float acc2[2][4];
#pragma unroll
    for (int i = 0; i < 2; ++i)
#pragma unroll
        for (int j = 0; j < 4; ++j) acc2[i][j] = 0.f;

#pragma unroll 2
    for (int k4 = 0; k4 < 16; ++k4) {
        float4 b0 = *(const float4*)&sW[(4 * k4 + 0) * 64 + 4 * tx];
        float4 b1v = *(const float4*)&sW[(4 * k4 + 1) * 64 + 4 * tx];
        float4 b2 = *(const float4*)&sW[(4 * k4 + 2) * 64 + 4 * tx];
        float4 b3 = *(const float4*)&sW[(4 * k4 + 3) * 64 + 4 * tx];
#pragma unroll
        for (int i = 0; i < 2; ++i) {
            int r = 2 * ty + i;
            float4 a = *(const float4*)&sX[r * 64 + ((k4 ^ (r & 7)) << 2)];
            acc2[i][0] = fmaf(a.x, b0.x, acc2[i][0]);
            acc2[i][1] = fmaf(a.x, b0.y, acc2[i][1]);
            acc2[i][2] = fmaf(a.x, b0.z, acc2[i][2]);
            acc2[i][3] = fmaf(a.x, b0.w, acc2[i][3]);
            acc2[i][0] = fmaf(a.y, b1v.x, acc2[i][0]);
            acc2[i][1] = fmaf(a.y, b1v.y, acc2[i][1]);
            acc2[i][2] = fmaf(a.y, b1v.z, acc2[i][2]);
            acc2[i][3] = fmaf(a.y, b1v.w, acc2[i][3]);
            acc2[i][0] = fmaf(a.z, b2.x, acc2[i][0]);
            acc2[i][1] = fmaf(a.z, b2.y, acc2[i][1]);
            acc2[i][2] = fmaf(a.z, b2.z, acc2[i][2]);
            acc2[i][3] = fmaf(a.z, b2.w, acc2[i][3]);
            acc2[i][0] = fmaf(a.w, b3.x, acc2[i][0]);
            acc2[i][1] = fmaf(a.w, b3.y, acc2[i][1]);
            acc2[i][2] = fmaf(a.w, b3.z, acc2[i][2]);
            acc2[i][3] = fmaf(a.w, b3.w, acc2[i][3]);
        }
    }

#pragma unroll
    for (int i = 0; i < 2; ++i) {
        int grow = node0 + 2 * ty + i;
        if (grow < n_nodes) {
            float dvv = dinv[grow];
            union { __half2 h[2]; uint2 u; } pk;
            pk.h[0] = __floats2half2_rn(acc2[i][0] * dvv, acc2[i][1] * dvv);
            pk.h[1] = __floats2half2_rn(acc2[i][2] * dvv, acc2[i][3] * dvv);
            *(uint2*)&H2[(size_t)grow * 64 + 4 * tx] = pk.u;
        }
    }
}

// --- final gather-aggregate + epilogue (fp16 rows, fp32 out) ---------------
__global__ void k_gather_agg(const __half* __restrict__ Hp, const int* __restrict__ offsets,
                             const int* __restrict__ degi,
                             const unsigned short* __restrict__ edge_src,
                             const float* __restrict__ dinv, const float* __restrict__ b,
                             float* __restrict__ out, int n_nodes) {
    int node = blockIdx.x * (THREADS / 8) + (threadIdx.x >> 3);
    if (node >= n_nodes) return;
    int l = threadIdx.x & 7;
    float2 acc[4];
    gather_node(acc, Hp, node, l, offsets, degi, edge_src);

    float dv = dinv[node];
    const float* bp = b + (l << 3);
    float* op = out + ((size_t)node << 6) + (l << 3);
    float4 o0, o1;
    o0.x = fmaxf(fmaf(acc[0].x, dv, bp[0]), 0.0f);
    o0.y = fmaxf(fmaf(acc[0].y, dv, bp[1]), 0.0f);
    o0.z = fmaxf(fmaf(acc[1].x, dv, bp[2]), 0.0f);
    o0.w = fmaxf(fmaf(acc[1].y, dv, bp[3]), 0.0f);
    o1.x = fmaxf(fmaf(acc[2].x, dv, bp[4]), 0.0f);
    o1.y = fmaxf(fmaf(acc[2].y, dv, bp[5]), 0.0f);
    o1.z = fmaxf(fmaf(acc[3].x, dv, bp[6]), 0.0f);
    o1.w = fmaxf(fmaf(acc[3].y, dv, bp[7]), 0.0f);
    *(float4*)op = o0;
    *(float4*)(op + 4) = o1;
}

extern "C" void kernel_launch(void* const* d_in, const int* in_sizes, int n_in,
                              void* d_out, int out_size, void* d_ws, size_t ws_size,
                              hipStream_t stream) {
    const float* x  = (const float*)d_in[0];
    const int*   ei = (const int*)d_in[1];   // [2, E] int32
    const float* W1 = (const float*)d_in[2];
    const float* b1 = (const float*)d_in[3];
    const float* W2 = (const float*)d_in[4];
    const float* b2 = (const float*)d_in[5];
    float* out = (float*)d_out;

    const int n_feat  = 128;
    const int n_nodes = in_sizes[0] / n_feat;   // 50000
    const int n_edges = in_sizes[1] / 2;        // 800000
    const int* src = ei;
    const int* dst = ei + n_edges;
    const int nbins = (n_nodes + BINW - 1) >> BINSH;          // 391
    const int nblk  = (n_edges + 4095) / 4096;                // 196

    // workspace layout (4B units, 16B-aligned chunks)
    const size_t n_pad = (size_t)((n_nodes + 63) & ~63);
    float* dinv        = (float*)d_ws;                        // n_pad
    int*   degi        = (int*)(dinv + n_pad);                // n_pad
    int*   offsets     = degi + n_pad;                        // n_pad
    int*   bin_cursor  = offsets + n_pad;                     // 512
    unsigned int* edge_binned = (unsigned int*)(bin_cursor + 512);     // MAXBINS*CAP u32
    unsigned short* edge_src  = (unsigned short*)(edge_binned + (size_t)MAXBINS * CAP); // MAXBINS*CAP u16
    __half* h1         = (__half*)(edge_src + (size_t)MAXBINS * CAP);  // n_nodes*64 fp16
    __half* h2         = h1 + (size_t)n_nodes * 64;           // n_nodes*64 fp16

    // ---- preprocessing (once per call; reused by both layers) ----
    k_init_cursor<<<2, THREADS, 0, stream>>>(bin_cursor, nbins);
    k_bin_scatter<<<nblk, 512, 0, stream>>>(src, dst, bin_cursor, edge_binned, n_edges);
    k_csr_build<<<nbins, 512, 0, stream>>>(
        edge_binned, bin_cursor, edge_src, offsets, degi, dinv, n_nodes);

    const int gemm_blocks = (n_nodes + 63) / 64;
    const int fuse_blocks = (n_nodes + 63) / 64;
    const int agg_blocks = (n_nodes + (THREADS / 8) - 1) / (THREADS / 8);

    // ---- layer 1 GEMM: h1 = fp16(dinv .* (x @ W1)) ----
    k_gemm<128><<<gemm_blocks, THREADS, 0, stream>>>(x, W1, dinv, h1, n_nodes);
    // ---- fused: layer-1 gather+relu -> layer-2 GEMM -> h2 ----
    k_agg_gemm<<<fuse_blocks, 512, 0, stream>>>(
        h1, offsets, degi, edge_src, dinv, b1, W2, h2, n_nodes);
    // ---- layer 2 gather + epilogue -> out ----
    k_gather_agg<<<agg_blocks, THREADS, 0, stream>>>(
        h2, offsets, degi, edge_src, dinv, b2, out, n_nodes);
}

// Round 18
// 86.534 us; speedup vs baseline: 1.0197x; 1.0197x over previous
//
#include <hip/hip_runtime.h>
#include <hip/hip_bf16.h>
#include <hip/hip_fp16.h>

// ---------------------------------------------------------------------------
// 2-layer GCN (PyG GCNConv semantics) on MI355X.
//   out[d] = relu( dinv[d]*( sum_e H'[src_e] + H'[d] ) + b ),  H' = dinv .* (X@W)
// R1..R11: CSR-gather; binned scatter; register-tiled GEMM; fp16 H'; fused
//          layer1-gather+layer2-GEMM. 103.5us.
// R12: partial-hist scan -- REGRESSED. R13: revert +128-row bins. 104.2us.
// R14: cooperative 5-in-1 preprocess -- REGRESSED (grid.sync spin). 185us.
// R15: fixed-capacity bins (no hist/scan pre-pass). 88.5us.
// R16: ushort edge_src; 512-thread preprocess blocks. 86.7us.  <-- BEST
// R17: 64-node agg_gemm -- REGRESSED (gather-phase occupancy). 88.2us.
// R17->R18: pure revert to R16 (measured best).
// ---------------------------------------------------------------------------

#define THREADS 256
#define BINSH 7                   // 128 rows per bin
#define BINW (1 << BINSH)
#define MAXBINS 512               // >= nbins = ceil(50000/128) = 391
#define CAPSH 12                  // 4096 slots per bin (mean fill ~2048)
#define CAP (1 << CAPSH)

__device__ inline int wave_incl_scan(int v, int lane) {
#pragma unroll
    for (int ofs = 1; ofs < 64; ofs <<= 1) {
        int t = __shfl_up(v, ofs, 64);
        if (lane >= ofs) v += t;
    }
    return v;
}

// --- init per-bin cursors to bin*CAP ---------------------------------------
__global__ void k_init_cursor(int* __restrict__ bin_cursor, int nbins) {
    int i = blockIdx.x * blockDim.x + threadIdx.x;
    if (i < nbins) bin_cursor[i] = i << CAPSH;
}

// --- pass 1: bin edges by 128-row dst-bin into fixed-cap slots -------------
// 512 threads x 8 edges = 4096 edges/block. packed = (src<<7) | (dst & 127).
__global__ __launch_bounds__(512)
void k_bin_scatter(const int* __restrict__ src, const int* __restrict__ dst,
                   int* __restrict__ bin_cursor, unsigned int* __restrict__ edge_binned,
                   int n_edges) {
    __shared__ int cnt[512];
    __shared__ int lbase[512];
    __shared__ int gbase[512];
    __shared__ int run[512];
    __shared__ int wsum[8];
    __shared__ unsigned int staged[4096];
    __shared__ unsigned short binarr[4096];
    const int tid = threadIdx.x;
    const int lane = tid & 63;
    const int wid = tid >> 6;
    const int base = blockIdx.x * 4096 + tid * 8;
    cnt[tid] = 0;
    run[tid] = 0;
    __syncthreads();

    int dv[8], sv[8];
    int nv = (base < n_edges) ? min(8, n_edges - base) : 0;
    if (nv == 8) {
        int4 a = *(const int4*)&dst[base];
        int4 b = *(const int4*)&dst[base + 4];
        dv[0] = a.x; dv[1] = a.y; dv[2] = a.z; dv[3] = a.w;
        dv[4] = b.x; dv[5] = b.y; dv[6] = b.z; dv[7] = b.w;
        a = *(const int4*)&src[base];
        b = *(const int4*)&src[base + 4];
        sv[0] = a.x; sv[1] = a.y; sv[2] = a.z; sv[3] = a.w;
        sv[4] = b.x; sv[5] = b.y; sv[6] = b.z; sv[7] = b.w;
    } else {
        for (int j = 0; j < nv; ++j) {
            dv[j] = dst[base + j];
            sv[j] = src[base + j];
        }
    }
    for (int j = 0; j < nv; ++j) atomicAdd(&cnt[dv[j] >> BINSH], 1);
    __syncthreads();
    int mycnt = cnt[tid];
    int s = wave_incl_scan(mycnt, lane);
    if (lane == 63) wsum[wid] = s;
    __syncthreads();
    if (wid == 0) {
        int t = (lane < 8) ? wsum[lane] : 0;
        int t2 = wave_incl_scan(t, lane);
        if (lane < 8) wsum[lane] = t2;
    }
    __syncthreads();
    int incl = s + ((wid > 0) ? wsum[wid - 1] : 0);
    lbase[tid] = incl - mycnt;
    if (mycnt > 0) gbase[tid] = atomicAdd(&bin_cursor[tid], mycnt);
    __syncthreads();
    for (int j = 0; j < nv; ++j) {
        int bn = dv[j] >> BINSH;
        int rank = atomicAdd(&run[bn], 1);
        int lp = lbase[bn] + rank;
        staged[lp] = ((unsigned)sv[j] << BINSH) | (unsigned)(dv[j] & (BINW - 1));
        binarr[lp] = (unsigned short)bn;
    }
    __syncthreads();
    int tot = wsum[7];
    for (int slot = tid; slot < tot; slot += 512) {
        int bn = binarr[slot];
        edge_binned[gbase[bn] + (slot - lbase[bn])] = staged[slot];
    }
}

// --- pass 2: per-bin degree count + scan + exact CSR (ushort) + metadata ---
// one block (512 thr) per 128-row bin; bin window = [b*CAP, bin_cursor[b]).
__global__ __launch_bounds__(512)
void k_csr_build(const unsigned int* __restrict__ edge_binned,
                 const int* __restrict__ bin_cursor,
                 unsigned short* __restrict__ edge_src,
                 int* __restrict__ offsets, int* __restrict__ degi,
                 float* __restrict__ dinv, int n_nodes) {
    __shared__ int lcnt[BINW];
    __shared__ int sc[BINW];
    __shared__ int lcur[BINW];
    const int b = blockIdx.x;
    const int node0 = b << BINSH;
    const int tid = threadIdx.x;
    const int ebeg = b << CAPSH;
    const int eend = bin_cursor[b];

    if (tid < BINW) lcnt[tid] = 0;
    __syncthreads();
    for (int k = ebeg + tid; k < eend; k += 512)
        atomicAdd(&lcnt[edge_binned[k] & (BINW - 1u)], 1);
    __syncthreads();

    if (tid < BINW) sc[tid] = lcnt[tid];
    __syncthreads();
    for (int ofs = 1; ofs < BINW; ofs <<= 1) {
        int v = 0;
        if (tid < BINW && tid >= ofs) v = sc[tid - ofs];
        __syncthreads();
        if (tid < BINW) sc[tid] += v;
        __syncthreads();
    }
    if (tid < BINW) {
        int cntv = lcnt[tid];
        int excl = ebeg + sc[tid] - cntv;
        lcur[tid] = excl;
        int node = node0 + tid;
        if (node < n_nodes) {
            offsets[node] = excl;
            degi[node] = cntv;
            dinv[node] = 1.0f / sqrtf((float)(1 + cntv));
        }
    }
    __syncthreads();
    for (int k = ebeg + tid; k < eend; k += 512) {
        unsigned p = edge_binned[k];
        int pos = atomicAdd(&lcur[p & (BINW - 1u)], 1);
        edge_src[pos] = (unsigned short)(p >> BINSH);
    }
}

// --- register-tiled GEMM: H'[r,:] = fp16( dinv[r] * (X[r,:K] @ W[K,64]) ) --
template <int K>
__global__ __launch_bounds__(256, 2)
void k_gemm(const float* __restrict__ X, const float* __restrict__ W,
            const float* __restrict__ dinv, __half* __restrict__ H, int n_rows) {
    constexpr int KQ = K / 4;
    constexpr int RSH = (KQ == 32) ? 5 : 4;
    __shared__ float sW[K * 64];
    __shared__ float sX[64 * K];
    const int tid = threadIdx.x;
    const int row0 = blockIdx.x * 64;

#pragma unroll
    for (int it = 0; it < (K * 64 / 4) / THREADS; ++it) {
        int idx = it * THREADS + tid;
        ((float4*)sW)[idx] = ((const float4*)W)[idx];
    }
#pragma unroll
    for (int it = 0; it < (64 * KQ) / THREADS; ++it) {
        int idx = it * THREADS + tid;
        int kq = idx & (KQ - 1);
        int r = idx >> RSH;
        float4 g = make_float4(0.f, 0.f, 0.f, 0.f);
        int grow = row0 + r;
        if (grow < n_rows) g = *(const float4*)&X[(size_t)grow * K + 4 * kq];
        *(float4*)&sX[r * K + ((kq ^ (r & 7)) << 2)] = g;
    }
    __syncthreads();

    const int tx = tid & 15;
    const int ty = tid >> 4;
    float acc[4][4];
#pragma unroll
    for (int i = 0; i < 4; ++i)
#pragma unroll
        for (int j = 0; j < 4; ++j) acc[i][j] = 0.f;

#pragma unroll 2
    for (int k4 = 0; k4 < KQ; ++k4) {
        float4 b0 = *(const float4*)&sW[(4 * k4 + 0) * 64 + 4 * tx];
        float4 b1 = *(const float4*)&sW[(4 * k4 + 1) * 64 + 4 * tx];
        float4 b2 = *(const float4*)&sW[(4 * k4 + 2) * 64 + 4 * tx];
        float4 b3 = *(const float4*)&sW[(4 * k4 + 3) * 64 + 4 * tx];
#pragma unroll
        for (int i = 0; i < 4; ++i) {
            int r = 4 * ty + i;
            float4 a = *(const float4*)&sX[r * K + ((k4 ^ (r & 7)) << 2)];
            acc[i][0] = fmaf(a.x, b0.x, acc[i][0]);
            acc[i][1] = fmaf(a.x, b0.y, acc[i][1]);
            acc[i][2] = fmaf(a.x, b0.z, acc[i][2]);
            acc[i][3] = fmaf(a.x, b0.w, acc[i][3]);
            acc[i][0] = fmaf(a.y, b1.x, acc[i][0]);
            acc[i][1] = fmaf(a.y, b1.y, acc[i][1]);
            acc[i][2] = fmaf(a.y, b1.z, acc[i][2]);
            acc[i][3] = fmaf(a.y, b1.w, acc[i][3]);
            acc[i][0] = fmaf(a.z, b2.x, acc[i][0]);
            acc[i][1] = fmaf(a.z, b2.y, acc[i][1]);
            acc[i][2] = fmaf(a.z, b2.z, acc[i][2]);
            acc[i][3] = fmaf(a.z, b2.w, acc[i][3]);
            acc[i][0] = fmaf(a.w, b3.x, acc[i][0]);
            acc[i][1] = fmaf(a.w, b3.y, acc[i][1]);
            acc[i][2] = fmaf(a.w, b3.z, acc[i][2]);
            acc[i][3] = fmaf(a.w, b3.w, acc[i][3]);
        }
    }

#pragma unroll
    for (int i = 0; i < 4; ++i) {
        int grow = row0 + 4 * ty + i;
        if (grow < n_rows) {
            float dvv = dinv[grow];
            union { __half2 h[2]; uint2 u; } pk;
            pk.h[0] = __floats2half2_rn(acc[i][0] * dvv, acc[i][1] * dvv);
            pk.h[1] = __floats2half2_rn(acc[i][2] * dvv, acc[i][3] * dvv);
            *(uint2*)&H[(size_t)grow * 64 + 4 * tx] = pk.u;
        }
    }
}

// --- fp16 row accumulate helper --------------------------------------------
__device__ inline void acc_row16(float2 acc[4], uint4 u) {
    const __half2* hp = (const __half2*)&u;
    float2 a = __half22float2(hp[0]);
    float2 b = __half22float2(hp[1]);
    float2 c = __half22float2(hp[2]);
    float2 d = __half22float2(hp[3]);
    acc[0].x += a.x; acc[0].y += a.y;
    acc[1].x += b.x; acc[1].y += b.y;
    acc[2].x += c.x; acc[2].y += c.y;
    acc[3].x += d.x; acc[3].y += d.y;
}

// gather one node's aggregate: acc = H'[node] + sum_e H'[src_e], half8 slot l
__device__ inline void gather_node(float2 acc[4], const __half* __restrict__ Hp,
                                   int node, int l, const int* __restrict__ offsets,
                                   const int* __restrict__ degi,
                                   const unsigned short* __restrict__ edge_src) {
    acc[0] = make_float2(0.f, 0.f); acc[1] = make_float2(0.f, 0.f);
    acc[2] = make_float2(0.f, 0.f); acc[3] = make_float2(0.f, 0.f);
    acc_row16(acc, *(const uint4*)(Hp + ((size_t)node << 6) + (l << 3)));  // self
    int start = offsets[node];
    int cnt = degi[node];
    int k = 0;
    for (; k + 8 <= cnt; k += 8) {
        int s0 = edge_src[start + k];
        int s1 = edge_src[start + k + 1];
        int s2 = edge_src[start + k + 2];
        int s3 = edge_src[start + k + 3];
        int s4 = edge_src[start + k + 4];
        int s5 = edge_src[start + k + 5];
        int s6 = edge_src[start + k + 6];
        int s7 = edge_src[start + k + 7];
        uint4 u0 = *(const uint4*)(Hp + ((size_t)s0 << 6) + (l << 3));
        uint4 u1 = *(const uint4*)(Hp + ((size_t)s1 << 6) + (l << 3));
        uint4 u2 = *(const uint4*)(Hp + ((size_t)s2 << 6) + (l << 3));
        uint4 u3 = *(const uint4*)(Hp + ((size_t)s3 << 6) + (l << 3));
        uint4 u4 = *(const uint4*)(Hp + ((size_t)s4 << 6) + (l << 3));
        uint4 u5 = *(const uint4*)(Hp + ((size_t)s5 << 6) + (l << 3));
        uint4 u6 = *(const uint4*)(Hp + ((size_t)s6 << 6) + (l << 3));
        uint4 u7 = *(const uint4*)(Hp + ((size_t)s7 << 6) + (l << 3));
        acc_row16(acc, u0); acc_row16(acc, u1); acc_row16(acc, u2); acc_row16(acc, u3);
        acc_row16(acc, u4); acc_row16(acc, u5); acc_row16(acc, u6); acc_row16(acc, u7);
    }
    for (; k + 4 <= cnt; k += 4) {
        int s0 = edge_src[start + k];
        int s1 = edge_src[start + k + 1];
        int s2 = edge_src[start + k + 2];
        int s3 = edge_src[start + k + 3];
        uint4 u0 = *(const uint4*)(Hp + ((size_t)s0 << 6) + (l << 3));
        uint4 u1 = *(const uint4*)(Hp + ((size_t)s1 << 6) + (l << 3));
        uint4 u2 = *(const uint4*)(Hp + ((size_t)s2 << 6) + (l << 3));
        uint4 u3 = *(const uint4*)(Hp + ((size_t)s3 << 6) + (l << 3));
        acc_row16(acc, u0); acc_row16(acc, u1); acc_row16(acc, u2); acc_row16(acc, u3);
    }
    for (; k < cnt; ++k) {
        int s0 = edge_src[start + k];
        acc_row16(acc, *(const uint4*)(Hp + ((size_t)s0 << 6) + (l << 3)));
    }
}

// --- fused: layer-1 gather+epilogue -> LDS tile -> layer-2 GEMM -> h2 fp16 -
__global__ __launch_bounds__(256)
void k_agg_gemm(const __half* __restrict__ Hp, const int* __restrict__ offsets,
                const int* __restrict__ degi, const unsigned short* __restrict__ edge_src,
                const float* __restrict__ dinv, const float* __restrict__ b1,
                const float* __restrict__ W2, __half* __restrict__ H2, int n_nodes) {
    __shared__ float sX[32 * 64];
    __shared__ float sW[64 * 64];
    const int tid = threadIdx.x;
    const int node0 = blockIdx.x * 32;

#pragma unroll
    for (int it = 0; it < 4; ++it)
        ((float4*)sW)[it * 256 + tid] = ((const float4*)W2)[it * 256 + tid];

    {
        const int r = tid >> 3;
        const int l = tid & 7;
        const int node = node0 + r;
        float v[8];
        if (node < n_nodes) {
            float2 acc[4];
            gather_node(acc, Hp, node, l, offsets, degi, edge_src);
            float dv = dinv[node];
            const float* bp = b1 + (l << 3);
            v[0] = fmaxf(fmaf(acc[0].x, dv, bp[0]), 0.f);
            v[1] = fmaxf(fmaf(acc[0].y, dv, bp[1]), 0.f);
            v[2] = fmaxf(fmaf(acc[1].x, dv, bp[2]), 0.f);
            v[3] = fmaxf(fmaf(acc[1].y, dv, bp[3]), 0.f);
            v[4] = fmaxf(fmaf(acc[2].x, dv, bp[4]), 0.f);
            v[5] = fmaxf(fmaf(acc[2].y, dv, bp[5]), 0.f);
            v[6] = fmaxf(fmaf(acc[3].x, dv, bp[6]), 0.f);
            v[7] = fmaxf(fmaf(acc[3].y, dv, bp[7]), 0.f);
        } else {
#pragma unroll
            for (int j = 0; j < 8; ++j) v[j] = 0.f;
        }
        *(float4*)&sX[r * 64 + (((2 * l + 0) ^ (r & 7)) << 2)] =
            make_float4(v[0], v[1], v[2], v[3]);
        *(float4*)&sX[r * 64 + (((2 * l + 1) ^ (r & 7)) << 2)] =
            make_float4(v[4], v[5], v[6], v[7]);
    }
    __syncthreads();

    const int tx = tid & 15;
    const int ty = tid >> 4;
    float acc2[2][4];
#pragma unroll
    for (int i = 0; i < 2; ++i)
#pragma unroll
        for (int j = 0; j < 4; ++j) acc2[i][j] = 0.f;

#pragma unroll 2
    for (int k4 = 0; k4 < 16; ++k4) {
        float4 b0 = *(const float4*)&sW[(4 * k4 + 0) * 64 + 4 * tx];
        float4 b1v = *(const float4*)&sW[(4 * k4 + 1) * 64 + 4 * tx];
        float4 b2 = *(const float4*)&sW[(4 * k4 + 2) * 64 + 4 * tx];
        float4 b3 = *(const float4*)&sW[(4 * k4 + 3) * 64 + 4 * tx];
#pragma unroll
        for (int i = 0; i < 2; ++i) {
            int r = 2 * ty + i;
            float4 a = *(const float4*)&sX[r * 64 + ((k4 ^ (r & 7)) << 2)];
            acc2[i][0] = fmaf(a.x, b0.x, acc2[i][0]);
            acc2[i][1] = fmaf(a.x, b0.y, acc2[i][1]);
            acc2[i][2] = fmaf(a.x, b0.z, acc2[i][2]);
            acc2[i][3] = fmaf(a.x, b0.w, acc2[i][3]);
            acc2[i][0] = fmaf(a.y, b1v.x, acc2[i][0]);
            acc2[i][1] = fmaf(a.y, b1v.y, acc2[i][1]);
            acc2[i][2] = fmaf(a.y, b1v.z, acc2[i][2]);
            acc2[i][3] = fmaf(a.y, b1v.w, acc2[i][3]);
            acc2[i][0] = fmaf(a.z, b2.x, acc2[i][0]);
            acc2[i][1] = fmaf(a.z, b2.y, acc2[i][1]);
            acc2[i][2] = fmaf(a.z, b2.z, acc2[i][2]);
            acc2[i][3] = fmaf(a.z, b2.w, acc2[i][3]);
            acc2[i][0] = fmaf(a.w, b3.x, acc2[i][0]);
            acc2[i][1] = fmaf(a.w, b3.y, acc2[i][1]);
            acc2[i][2] = fmaf(a.w, b3.z, acc2[i][2]);
            acc2[i][3] = fmaf(a.w, b3.w, acc2[i][3]);
        }
    }

#pragma unroll
    for (int i = 0; i < 2; ++i) {
        int grow = node0 + 2 * ty + i;
        if (grow < n_nodes) {
            float dvv = dinv[grow];
            union { __half2 h[2]; uint2 u; } pk;
            pk.h[0] = __floats2half2_rn(acc2[i][0] * dvv, acc2[i][1] * dvv);
            pk.h[1] = __floats2half2_rn(acc2[i][2] * dvv, acc2[i][3] * dvv);
            *(uint2*)&H2[(size_t)grow * 64 + 4 * tx] = pk.u;
        }
    }
}

// --- final gather-aggregate + epilogue (fp16 rows, fp32 out) ---------------
__global__ void k_gather_agg(const __half* __restrict__ Hp, const int* __restrict__ offsets,
                             const int* __restrict__ degi,
                             const unsigned short* __restrict__ edge_src,
                             const float* __restrict__ dinv, const float* __restrict__ b,
                             float* __restrict__ out, int n_nodes) {
    int node = blockIdx.x * (THREADS / 8) + (threadIdx.x >> 3);
    if (node >= n_nodes) return;
    int l = threadIdx.x & 7;
    float2 acc[4];
    gather_node(acc, Hp, node, l, offsets, degi, edge_src);

    float dv = dinv[node];
    const float* bp = b + (l << 3);
    float* op = out + ((size_t)node << 6) + (l << 3);
    float4 o0, o1;
    o0.x = fmaxf(fmaf(acc[0].x, dv, bp[0]), 0.0f);
    o0.y = fmaxf(fmaf(acc[0].y, dv, bp[1]), 0.0f);
    o0.z = fmaxf(fmaf(acc[1].x, dv, bp[2]), 0.0f);
    o0.w = fmaxf(fmaf(acc[1].y, dv, bp[3]), 0.0f);
    o1.x = fmaxf(fmaf(acc[2].x, dv, bp[4]), 0.0f);
    o1.y = fmaxf(fmaf(acc[2].y, dv, bp[5]), 0.0f);
    o1.z = fmaxf(fmaf(acc[3].x, dv, bp[6]), 0.0f);
    o1.w = fmaxf(fmaf(acc[3].y, dv, bp[7]), 0.0f);
    *(float4*)op = o0;
    *(float4*)(op + 4) = o1;
}

extern "C" void kernel_launch(void* const* d_in, const int* in_sizes, int n_in,
                              void* d_out, int out_size, void* d_ws, size_t ws_size,
                              hipStream_t stream) {
    const float* x  = (const float*)d_in[0];
    const int*   ei = (const int*)d_in[1];   // [2, E] int32
    const float* W1 = (const float*)d_in[2];
    const float* b1 = (const float*)d_in[3];
    const float* W2 = (const float*)d_in[4];
    const float* b2 = (const float*)d_in[5];
    float* out = (float*)d_out;

    const int n_feat  = 128;
    const int n_nodes = in_sizes[0] / n_feat;   // 50000
    const int n_edges = in_sizes[1] / 2;        // 800000
    const int* src = ei;
    const int* dst = ei + n_edges;
    const int nbins = (n_nodes + BINW - 1) >> BINSH;          // 391
    const int nblk  = (n_edges + 4095) / 4096;                // 196

    // workspace layout (4B units, 16B-aligned chunks)
    const size_t n_pad = (size_t)((n_nodes + 63) & ~63);
    float* dinv        = (float*)d_ws;                        // n_pad
    int*   degi        = (int*)(dinv + n_pad);                // n_pad
    int*   offsets     = degi + n_pad;                        // n_pad
    int*   bin_cursor  = offsets + n_pad;                     // 512
    unsigned int* edge_binned = (unsigned int*)(bin_cursor + 512);     // MAXBINS*CAP u32
    unsigned short* edge_src  = (unsigned short*)(edge_binned + (size_t)MAXBINS * CAP); // MAXBINS*CAP u16
    __half* h1         = (__half*)(edge_src + (size_t)MAXBINS * CAP);  // n_nodes*64 fp16
    __half* h2         = h1 + (size_t)n_nodes * 64;           // n_nodes*64 fp16

    // ---- preprocessing (once per call; reused by both layers) ----
    k_init_cursor<<<2, THREADS, 0, stream>>>(bin_cursor, nbins);
    k_bin_scatter<<<nblk, 512, 0, stream>>>(src, dst, bin_cursor, edge_binned, n_edges);
    k_csr_build<<<nbins, 512, 0, stream>>>(
        edge_binned, bin_cursor, edge_src, offsets, degi, dinv, n_nodes);

    const int gemm_blocks = (n_nodes + 63) / 64;
    const int fuse_blocks = (n_nodes + 31) / 32;
    const int agg_blocks = (n_nodes + (THREADS / 8) - 1) / (THREADS / 8);

    // ---- layer 1 GEMM: h1 = fp16(dinv .* (x @ W1)) ----
    k_gemm<128><<<gemm_blocks, THREADS, 0, stream>>>(x, W1, dinv, h1, n_nodes);
    // ---- fused: layer-1 gather+relu -> layer-2 GEMM -> h2 ----
    k_agg_gemm<<<fuse_blocks, THREADS, 0, stream>>>(
        h1, offsets, degi, edge_src, dinv, b1, W2, h2, n_nodes);
    // ---- layer 2 gather + epilogue -> out ----
    k_gather_agg<<<agg_blocks, THREADS, 0, stream>>>(
        h2, offsets, degi, edge_src, dinv, b2, out, n_nodes);
}